// Round 3
// baseline (371.142 us; speedup 1.0000x reference)
//
#include <hip/hip_runtime.h>

#define LOG2E 1.4426950408889634f
#define LN2   0.6931471805599453f

namespace {
constexpr int B    = 64;
constexpr int T    = 2000;
constexpr int V    = 256;
constexpr int S    = 400;
constexpr int CHK  = 8;
constexpr int NCTP = 250;                 // chunks stored in G
constexpr int KP   = 408;                 // padded k rows (401 used)
constexpr size_t GELEM  = (size_t)B * NCTP * KP * 8;
constexpr size_t GBYTES = GELEM * 2;      // 104,448,000 B
constexpr size_t LAOFF  = GBYTES / 4;     // float offset of la in ws
constexpr size_t LGOFF  = LAOFF + 64 * 1024;
constexpr size_t REQBYTES = GBYTES + 2 * 64 * 1024 * 4;   // 104,972,288
constexpr int LSTR = 260;                 // gather LDS row stride
constexpr int NW7  = 7;                   // fallback params
constexpr int NCT7 = 250;
constexpr int BST7 = 12;
constexpr int SLOTR = 448;                // ring slot rows (448*16B = 7168B)
}

using h8 = __attribute__((ext_vector_type(8))) _Float16;

__device__ __forceinline__ float fexp2(float x){ return __builtin_amdgcn_exp2f(x); }
__device__ __forceinline__ float flog2(float x){ return __builtin_amdgcn_logf(x); }

// lane i <- lane i-1 (0 for lane 0)
__device__ __forceinline__ float wave_shr1(float x) {
  int v = __builtin_amdgcn_update_dpp(0, __builtin_bit_cast(int, x),
                                      0x138, 0xf, 0xf, true);
  return __builtin_bit_cast(float, v);
}
__device__ __forceinline__ int wave_shr1_i(int x) {
  return __builtin_amdgcn_update_dpp(0, x, 0x138, 0xf, 0xf, true);
}
// lane i <- lane i+1 (0 for lane 63)
__device__ __forceinline__ float wave_shl1(float x) {
  int v = __builtin_amdgcn_update_dpp(0, __builtin_bit_cast(int, x),
                                      0x130, 0xf, 0xf, true);
  return __builtin_bit_cast(float, v);
}
__device__ __forceinline__ int wave_shl1_i(int x) {
  return __builtin_amdgcn_update_dpp(0, x, 0x130, 0xf, 0xf, true);
}

#define WAITVM49() asm volatile("s_waitcnt vmcnt(49)" ::: "memory")
#define WAITVM0()  asm volatile("s_waitcnt vmcnt(0)"  ::: "memory")
#define WAITLGKM() asm volatile("s_waitcnt lgkmcnt(0)" ::: "memory")

// ---------------- gather: G[b][c][k][j] = fp16(exp(lp[b][1+8c+j][col_k])) ----
__global__ __launch_bounds__(512)
void ctc_gather_kernel(const float* __restrict__ logp,
                       const int* __restrict__ targets,
                       _Float16* __restrict__ G)
{
  const int tile = blockIdx.x;            // 32 tiles of 64 t-values
  const int b    = blockIdx.y;
  const int tid  = threadIdx.x;
  const int i0   = tile * 64;
  const float* lp = logp + (size_t)b * T * V;
  const int*   tg = targets + (size_t)b * S;

  __shared__ float ls[64 * LSTR];         // 65 KB
  __shared__ int   tgs[S];

  for (int f = tid; f < 64 * 64; f += 512) {
    const int row = f >> 6, c4 = f & 63;
    int t = i0 + 1 + row; if (t > T - 1) t = T - 1;
    float4 v = ((const float4*)(lp + (size_t)t * V))[c4];
    *(float4*)&ls[row * LSTR + c4 * 4] = v;
  }
  for (int k = tid; k < S; k += 512) tgs[k] = tg[k];
  __syncthreads();

  const int w    = tid >> 6;
  const int lane = tid & 63;
  _Float16* gb = G + (size_t)b * NCTP * KP * 8;

  // 7 k-blocks x 8 chunks; lane produces 8 j-values for one k (16B store)
  for (int it = w; it < 56; it += 8) {
    const int kb = it >> 3;
    const int cc = it & 7;
    const int c  = tile * 8 + cc;
    if (c >= NCTP) continue;
    const int k = kb * 64 + lane;
    if (k >= KP) continue;
    const int e = (k < S) ? tgs[k] : 1;   // rows 400..407: blank/pad
    h8 hv;
    #pragma unroll
    for (int j = 0; j < 8; ++j)
      hv[j] = (_Float16)fexp2(ls[(cc * 8 + j) * LSTR + e] * LOG2E);
    *(h8*)(gb + ((size_t)c * KP + k) * 8) = hv;
  }
}

// ---------------- fwd/bwd meet-in-middle: ONE WAVE per (b,dir) --------------
// r13 post-mortem: register prefetch depth collapses under VGPR pressure
// (compiler reschedules loads next to uses; VGPR capped at 128).  This
// version stages G chunks into an 8-slot LDS ring via global_load_lds
// (zero VGPR cost) with explicit counted s_waitcnt vmcnt(49) -- 7 loads
// per chunk, 8 chunks in flight, never drained to 0.  Bank-conflict-free
// via row-index involution swizzle r ^ ((r>>3)&7) applied to BOTH the
// per-lane global source address (linear LDS write) and the ds_read
// address (rule #21: same involution both sides).
// 16-state/lane band layout + per-lane exponent E validated in r12/r13.
__global__ __launch_bounds__(64)
void ctc_fb_kernel(const float* __restrict__ logp,
                   const int* __restrict__ targets,
                   const int* __restrict__ input_len,
                   const int* __restrict__ target_len,
                   const _Float16* __restrict__ G,
                   float* __restrict__ la,
                   float* __restrict__ lg)
{
  const int b    = blockIdx.x;
  const int dir  = blockIdx.y;
  const int lane = threadIdx.x & 63;
  const float* __restrict__ lp = logp + (size_t)b * T * V;
  const int il = input_len[b];
  const int tl = target_len[b];
  const int m  = il >> 1;
  const int* tg = targets + (size_t)b * S;

  const _Float16* Gb = G + (size_t)b * NCTP * KP * 8;
  // lane l consumes G rows 8l..8l+7 (+ row 400 = blank). Lanes >= 51 own
  // only invalid states: clamp into blank-pad rows 400..407.
  const int krow = (8 * lane < KP - 8) ? 8 * lane : KP - 8;

  float skF[8], skB[8];
  #pragma unroll
  for (int j = 0; j < 8; ++j) {
    const int k   = 8 * lane + j;
    const int kc  = k < S ? k : S - 1;
    const int km  = (k - 1) < 0 ? 0 : ((k - 1) < S ? (k - 1) : S - 1);
    skF[j] = (k > 0 && tg[kc] != tg[km]) ? 1.0f : 0.0f;
    const int k2  = k + 1;
    const int k2c = k2 < S ? k2 : S - 1;
    const int k2m = (k2 - 1) < S ? (k2 - 1) : S - 1;
    skB[j] = (tg[k2c] != tg[k2m]) ? 1.0f : 0.0f;
  }

  __shared__ _Float16 ring[8][SLOTR * 8];   // 57,344 B

  // async-stage chunk into ring slot: linear LDS positions p=q*64+lane,
  // global source row = involution(p) so that position p holds row inv(p).
  auto stage = [&](int chunk, int slot) {
    if (chunk < 0) chunk = 0;
    if (chunk > NCTP - 1) chunk = NCTP - 1;
    const _Float16* src = Gb + (size_t)chunk * (KP * 8);
    #pragma unroll
    for (int q = 0; q < 7; ++q) {
      const int p = q * 64 + lane;
      int gr = p ^ ((p >> 3) & 7);
      if (gr > KP - 1) gr = 400;            // pad positions: any valid row
      __builtin_amdgcn_global_load_lds(src + (size_t)gr * 8,
                                       &ring[slot][(size_t)q * 64 * 8],
                                       16, 0, 0);
    }
  };

  // read this lane's 9 swizzled rows from a ring slot
  auto rdchunk = [&](int slot, h8 (&cur)[9]) {
    const _Float16* sl = &ring[slot][0];
    #pragma unroll
    for (int j = 0; j < 8; ++j) {
      const int r = krow + j;
      const int q = r ^ ((r >> 3) & 7);
      cur[j] = *(const h8*)(sl + (size_t)q * 8);
    }
    cur[8] = *(const h8*)(sl + (size_t)402 * 8);   // row 400 swizzled -> 402
  };

  if (dir == 0) {
    // ======================= FORWARD =======================
    float a[16];
    #pragma unroll
    for (int i = 0; i < 16; ++i) a[i] = 0.0f;
    int  E = 0;
    bool alive = (lane == 0);
    if (lane == 0) {
      a[0] = fexp2(lp[1] * LOG2E);          // t=0 blank
      a[1] = fexp2(lp[tg[0]] * LOG2E);      // t=0 first symbol
    }

    h8 cur[9];
    WAITVM0();                              // exact vmcnt bookkeeping from here
    #pragma unroll
    for (int k0 = 0; k0 < 8; ++k0) stage(k0, k0);
    WAITVM49();                             // chunk 0 resident
    __builtin_amdgcn_sched_barrier(0);
    rdchunk(0, cur);
    WAITLGKM();                             // cur in regs; slot 0 reusable
    __builtin_amdgcn_sched_barrier(0);

    const int NCH = (m + 7) >> 3;
    for (int n = 0; n < NCH; ++n) {
      stage(n + 8, n & 7);                  // refill just-freed slot

      const int E1 = wave_shr1_i(E);
      if (!alive) E = E1;
      int d = E1 - E; d = d > 126 ? 126 : (d < -126 ? -126 : d);
      const float f = ldexpf(1.0f, d);

      #pragma unroll
      for (int i = 0; i < 8; ++i) {
        const int t = 1 + n * CHK + i;
        if (t <= m) {                       // wave-uniform predicate
          const float pbi = (float)cur[8][i];
          const float h = wave_shr1(a[15]) * f;   // state 16l-1 (0 @ lane0)
          #pragma unroll
          for (int j = 7; j >= 0; --j) {    // descending: reads are pre-step
            const float psj = (float)cur[j][i];
            const float lo = j ? a[2 * j - 1] : h;
            a[2 * j + 1] = __builtin_fmaf(lo, skF[j],
                                          a[2 * j + 1] + a[2 * j]) * psj;
            a[2 * j]     = (a[2 * j] + lo) * pbi;
          }
        }
      }
      { // renorm
        float mx[8];
        #pragma unroll
        for (int q = 0; q < 8; ++q) mx[q] = fmaxf(a[2 * q], a[2 * q + 1]);
        #pragma unroll
        for (int q = 0; q < 4; ++q) mx[q] = fmaxf(mx[q], mx[q + 4]);
        const float m2 = fmaxf(fmaxf(mx[0], mx[1]), fmaxf(mx[2], mx[3]));
        int k = 0; (void)frexpf(m2, &k);
        #pragma unroll
        for (int i = 0; i < 16; ++i) a[i] = ldexpf(a[i], -k);
        E += k;
        alive = (m2 != 0.0f);
      }

      WAITVM49();                           // chunk n+1 resident
      __builtin_amdgcn_sched_barrier(0);
      rdchunk((n + 1) & 7, cur);
      WAITLGKM();                           // guards WAR with next stage()
      __builtin_amdgcn_sched_barrier(0);
    }

    float* dst = la + (size_t)b * 1024 + 16 * lane;
    #pragma unroll
    for (int i = 0; i < 16; ++i) dst[i] = flog2(a[i]) + (float)E;
  } else {
    // ======================= BACKWARD =======================
    float g[16];
    const int s0 = 16 * lane;
    bool alive = false;
    #pragma unroll
    for (int i = 0; i < 16; ++i) {
      const int s = s0 + i;
      g[i] = (s == 2 * tl || s == 2 * tl - 1) ? 1.0f : 0.0f;
      alive = alive || (g[i] != 0.0f);
    }
    int E = 0;

    const int c_hi = (il - 2) >> 3;         // >= 124 (il >= 1000)
    const int c_lo = m >> 3;                // >= 62

    h8 cur[9];
    WAITVM0();
    #pragma unroll
    for (int k0 = 0; k0 < 8; ++k0) stage(c_hi - k0, (c_hi - k0) & 7);
    WAITVM49();                             // chunk c_hi resident
    __builtin_amdgcn_sched_barrier(0);
    rdchunk(c_hi & 7, cur);
    WAITLGKM();
    __builtin_amdgcn_sched_barrier(0);

    for (int n = c_hi; n >= c_lo; --n) {
      stage(n - 8, (n - 8) & 7);

      const int E1 = wave_shl1_i(E);
      if (!alive) E = E1;
      int d = E1 - E; d = d > 126 ? 126 : (d < -126 ? -126 : d);
      const float f = ldexpf(1.0f, d);

      #pragma unroll
      for (int ii = 0; ii < 8; ++ii) {
        const int i = 7 - ii;
        const int row = 1 + n * CHK + i;    // emission row, processed hi->lo
        if (row > m && row < il) {          // wave-uniform predicate
          const float pbi = (float)cur[8][i];
          float pg[16];
          #pragma unroll
          for (int q = 0; q < 8; ++q) {
            pg[2 * q]     = g[2 * q]     * pbi;
            pg[2 * q + 1] = g[2 * q + 1] * (float)cur[q][i];
          }
          const float h0 = wave_shl1(pg[0]) * f;  // state 16(l+1)   (0 @ 63)
          const float h1 = wave_shl1(pg[1]) * f;  // state 16(l+1)+1 (0 @ 63)
          #pragma unroll
          for (int q = 0; q < 8; ++q) {
            const float u1 = (q < 7) ? pg[2 * q + 2] : h0;
            const float u2 = (q < 7) ? pg[2 * q + 3] : h1;
            g[2 * q + 1] = __builtin_fmaf(u2, skB[q], pg[2 * q + 1] + u1);
            g[2 * q]     = pg[2 * q] + pg[2 * q + 1];
          }
        }
      }
      {
        float mx[8];
        #pragma unroll
        for (int q = 0; q < 8; ++q) mx[q] = fmaxf(g[2 * q], g[2 * q + 1]);
        #pragma unroll
        for (int q = 0; q < 4; ++q) mx[q] = fmaxf(mx[q], mx[q + 4]);
        const float m2 = fmaxf(fmaxf(mx[0], mx[1]), fmaxf(mx[2], mx[3]));
        int k = 0; (void)frexpf(m2, &k);
        #pragma unroll
        for (int i = 0; i < 16; ++i) g[i] = ldexpf(g[i], -k);
        E += k;
        alive = (m2 != 0.0f);
      }

      WAITVM49();                           // chunk n-1 resident
      __builtin_amdgcn_sched_barrier(0);
      rdchunk((n - 1) & 7, cur);
      WAITLGKM();
      __builtin_amdgcn_sched_barrier(0);
    }

    float* dst = lg + (size_t)b * 1024 + 16 * lane;
    #pragma unroll
    for (int i = 0; i < 16; ++i) dst[i] = flog2(g[i]) + (float)E;
  }
}

// ---------------- merge: loss_b = -ln sum_{s<Lb} 2^(la+lg), mean ------------
__global__ __launch_bounds__(64)
void ctc_merge_kernel(const float* __restrict__ la,
                      const float* __restrict__ lg,
                      const int* __restrict__ target_len,
                      float* __restrict__ out)
{
  const int b    = blockIdx.x;
  const int lane = threadIdx.x;
  const int tl = target_len[b];
  const int Lb = 2 * tl + 1;
  const float* A  = la + (size_t)b * 1024;
  const float* Gm = lg + (size_t)b * 1024;

  float vs[16];
  float vmax = -1e30f;
  #pragma unroll
  for (int r = 0; r < 16; ++r) {
    const int s = lane + 64 * r;
    float x = A[s] + Gm[s];
    x = (s < Lb) ? x : -1e30f;
    vs[r] = x;
    vmax = fmaxf(vmax, x);
  }
  #pragma unroll
  for (int o = 32; o > 0; o >>= 1) vmax = fmaxf(vmax, __shfl_xor(vmax, o, 64));
  float sum = 0.0f;
  #pragma unroll
  for (int r = 0; r < 16; ++r) sum += fexp2(vs[r] - vmax);
  #pragma unroll
  for (int o = 32; o > 0; o >>= 1) sum += __shfl_xor(sum, o, 64);
  if (lane == 0) {
    const float ll = (vmax + flog2(sum)) * LN2;
    float loss = -ll;
    if (!(loss < 1e29f)) loss = 0.0f;
    atomicAdd(out, loss / ((float)tl * (float)B));
  }
}

// ---------------- fallback: round-6 kernel (validated), if ws too small -----
__global__ __launch_bounds__(NW7 * 64)
void ctc_alpha7_kernel(const float* __restrict__ logp,
                       const int* __restrict__ targets,
                       const int* __restrict__ input_len,
                       const int* __restrict__ target_len,
                       float* __restrict__ out)
{
  const int b    = blockIdx.x;
  const int tid  = threadIdx.x;
  const int w    = tid >> 6;
  const int lane = tid & 63;
  const bool lane0 = (lane == 0);
  const float* __restrict__ lp = logp + (size_t)b * T * V;
  const int il = input_len[b];
  const int tl = target_len[b];
  const int Lb = 2 * tl + 1;

  __shared__ float bnd[NW7 - 1][NCT7 * BST7];
  __shared__ int   cnt[NW7 - 1];
  __shared__ float pblk[T];
  __shared__ float afin[NW7 * 64 * 2];

  if (tid < NW7 - 1) cnt[tid] = 0;

  const int* tg = targets + (size_t)b * S;
  const int k1 = (tid < S) ? tid : (S - 1);
  const int e1 = tg[k1];
  const float sk1 = (k1 == 0 || e1 != tg[k1 - 1]) ? 1.0f : 0.0f;

  for (int i = tid; i < T; i += NW7 * 64) {
    int t = (i + 1 < T) ? (i + 1) : (T - 1);
    pblk[i] = fexp2(lp[(size_t)t * V + 1] * LOG2E);
  }
  __syncthreads();

  const bool active = (w * 128) < Lb;
  if (active) {
    float a0 = 0.0f, a1 = 0.0f;
    int   E  = 0;
    if (tid == 0) { a0 = fexp2(lp[1] * LOG2E); a1 = fexp2(lp[e1] * LOG2E); }

    float tokL[CHK];
    #pragma unroll
    for (int i = 0; i < CHK; ++i) tokL[i] = lp[(size_t)(1 + i) * V + e1];

    const int NCH = (il - 1 + CHK - 1) / CHK;
    for (int c = 0; c < NCH; ++c) {
      const int t0 = 1 + c * CHK;
      float tokP[CHK];
      #pragma unroll
      for (int i = 0; i < CHK; ++i) tokP[i] = fexp2(tokL[i] * LOG2E);
      float nl[CHK];
      if (c + 1 < NCT7) {
        #pragma unroll
        for (int i = 0; i < CHK; ++i) {
          int tt = t0 + CHK + i; if (tt > T - 1) tt = T - 1;
          nl[i] = lp[(size_t)tt * V + e1];
        }
      }
      float pbk[CHK];
      {
        float4 q0 = *(const float4*)&pblk[c * CHK];
        float4 q1 = *(const float4*)&pblk[c * CHK + 4];
        pbk[0]=q0.x; pbk[1]=q0.y; pbk[2]=q0.z; pbk[3]=q0.w;
        pbk[4]=q1.x; pbk[5]=q1.y; pbk[6]=q1.z; pbk[7]=q1.w;
      }
      float bq[CHK];
      int Ep = 0;
      if (w > 0) {
        while (__hip_atomic_load(&cnt[w - 1], __ATOMIC_ACQUIRE,
                                 __HIP_MEMORY_SCOPE_WORKGROUP) < c + 1)
          __builtin_amdgcn_s_sleep(1);
        const float* src = &bnd[w - 1][c * BST7];
        float4 q0 = *(const float4*)(src);
        float4 q1 = *(const float4*)(src + 4);
        bq[0]=q0.x; bq[1]=q0.y; bq[2]=q0.z; bq[3]=q0.w;
        bq[4]=q1.x; bq[5]=q1.y; bq[6]=q1.z; bq[7]=q1.w;
        Ep = __float_as_int(src[8]);
      } else {
        #pragma unroll
        for (int i = 0; i < CHK; ++i) bq[i] = 0.0f;
      }
      const float mz  = fmaxf(a0, a1);
      const int   E1o = __shfl_up(E, 1);
      const int   E8  = __shfl_up(E, 8);
      const int   E9  = __shfl_up(E, 9);
      const float mz1 = __shfl_up(mz, 1);
      if (mz == 0.0f) E = (lane < 8) ? Ep : E8;
      int E1 = (mz1 == 0.0f) ? ((lane <= 8) ? Ep : E9) : E1o;
      if (lane0) E1 = (w == 0) ? E : Ep;
      int d = E1 - E; d = d > 126 ? 126 : (d < -126 ? -126 : d);
      const float f = ldexpf(1.0f, d);
      const float a1s = a1;
      float pub[CHK];
      #pragma unroll
      for (int i = 0; i < CHK; ++i) {
        const int t = t0 + i;
        if (t < il) {
          float hl = wave_shr1(a1);
          hl = lane0 ? bq[i] : hl;
          hl *= f;
          float s01 = a1 + a0;
          a1 = __builtin_fmaf(hl, sk1, s01) * tokP[i];
          a0 = (a0 + hl) * pbk[i];
        }
        pub[i] = a1;
      }
      if (w < NW7 - 1 && lane == 63) {
        float* dst = &bnd[w][c * BST7];
        dst[0] = a1s;
        #pragma unroll
        for (int i = 0; i < CHK - 1; ++i) dst[1 + i] = pub[i];
        dst[8] = __int_as_float(E);
        __hip_atomic_store(&cnt[w], c + 1, __ATOMIC_RELEASE,
                           __HIP_MEMORY_SCOPE_WORKGROUP);
      }
      {
        float m2 = fmaxf(a0, a1);
        int k = 0;
        (void)frexpf(m2, &k);
        a0 = ldexpf(a0, -k);
        a1 = ldexpf(a1, -k);
        E += k;
      }
      #pragma unroll
      for (int i = 0; i < CHK; ++i) tokL[i] = nl[i];
    }
    afin[2 * tid]     = flog2(a0) + (float)E;
    afin[2 * tid + 1] = flog2(a1) + (float)E;
  }
  __syncthreads();

  if (tid == 0) {
    const float x = afin[2 * tl];
    const float y = afin[2 * tl - 1];
    const float mm = fmaxf(x, y);
    const float ll = (mm + flog2(fexp2(x - mm) + fexp2(y - mm))) * LN2;
    float loss = -ll;
    if (!(loss < 1e29f)) loss = 0.0f;
    atomicAdd(out, loss / ((float)tl * (float)B));
  }
}

__global__ void ctc_zero_kernel(float* __restrict__ out) { out[0] = 0.0f; }

extern "C" void kernel_launch(void* const* d_in, const int* in_sizes, int n_in,
                              void* d_out, int out_size, void* d_ws, size_t ws_size,
                              hipStream_t stream) {
  const float* logp    = (const float*)d_in[0];
  const int*   targets = (const int*)d_in[1];
  const int*   il      = (const int*)d_in[2];
  const int*   tl      = (const int*)d_in[3];
  float* out = (float*)d_out;

  ctc_zero_kernel<<<1, 1, 0, stream>>>(out);
  if (ws_size >= REQBYTES) {
    _Float16* G  = (_Float16*)d_ws;
    float*    la = (float*)d_ws + LAOFF;
    float*    lg = (float*)d_ws + LGOFF;
    ctc_gather_kernel<<<dim3(32, B), 512, 0, stream>>>(logp, targets, G);
    ctc_fb_kernel<<<dim3(B, 2), 64, 0, stream>>>(logp, targets, il, tl, G, la, lg);
    ctc_merge_kernel<<<B, 64, 0, stream>>>(la, lg, tl, out);
  } else {
    ctc_alpha7_kernel<<<B, NW7 * 64, 0, stream>>>(logp, targets, il, tl, out);
  }
}

// Round 4
// 341.367 us; speedup vs baseline: 1.0872x; 1.0872x over previous
//
#include <hip/hip_runtime.h>

#define LOG2E 1.4426950408889634f
#define LN2   0.6931471805599453f

namespace {
constexpr int B    = 64;
constexpr int T    = 2000;
constexpr int V    = 256;
constexpr int S    = 400;
constexpr int CHK  = 8;
constexpr int NCTP = 250;                 // chunks stored in G
constexpr int KP   = 408;                 // fragments per chunk (8*51)
constexpr size_t GELEM  = (size_t)B * NCTP * KP * 8;
constexpr size_t GBYTES = GELEM * 2;      // 104,448,000 B
constexpr size_t LAOFF  = GBYTES / 4;     // float offset of la in ws
constexpr size_t LGOFF  = LAOFF + 64 * 1024;
constexpr size_t REQBYTES = GBYTES + 2 * 64 * 1024 * 4;   // 104,972,288
constexpr int LSTR = 260;                 // gather LDS row stride
constexpr int NW7  = 7;                   // fallback params
constexpr int NCT7 = 250;
constexpr int BST7 = 12;
}

using h8 = __attribute__((ext_vector_type(8))) _Float16;

__device__ __forceinline__ float fexp2(float x){ return __builtin_amdgcn_exp2f(x); }
__device__ __forceinline__ float flog2(float x){ return __builtin_amdgcn_logf(x); }

// lane i <- lane i-1 (0 for lane 0)
__device__ __forceinline__ float wave_shr1(float x) {
  int v = __builtin_amdgcn_update_dpp(0, __builtin_bit_cast(int, x),
                                      0x138, 0xf, 0xf, true);
  return __builtin_bit_cast(float, v);
}
__device__ __forceinline__ int wave_shr1_i(int x) {
  return __builtin_amdgcn_update_dpp(0, x, 0x138, 0xf, 0xf, true);
}
// lane i <- lane i+1 (0 for lane 63)
__device__ __forceinline__ float wave_shl1(float x) {
  int v = __builtin_amdgcn_update_dpp(0, __builtin_bit_cast(int, x),
                                      0x130, 0xf, 0xf, true);
  return __builtin_bit_cast(float, v);
}
__device__ __forceinline__ int wave_shl1_i(int x) {
  return __builtin_amdgcn_update_dpp(0, x, 0x130, 0xf, 0xf, true);
}

// ---------------- gather ----------------------------------------------------
// G layout (r15): per (b,c), 408 fragments of 16B.  Fragment p = j*51 + l
// (j=0..7, l=0..50) holds fp16(exp(lp[1+8c+jj][ tgs[8l+j] ])) for jj=0..7,
// i.e. old row r = 8l+j.  k >= S  -> blank (rows 400..407 live at l=50).
// This makes fb's 9 per-chunk loads LANE-CONTIGUOUS (~57 cachelines/chunk
// instead of 576 with the old 128B-stride pattern).
__global__ __launch_bounds__(512)
void ctc_gather_kernel(const float* __restrict__ logp,
                       const int* __restrict__ targets,
                       _Float16* __restrict__ G)
{
  const int tile = blockIdx.x;            // 32 tiles of 64 t-values
  const int b    = blockIdx.y;
  const int tid  = threadIdx.x;
  const int i0   = tile * 64;
  const float* lp = logp + (size_t)b * T * V;
  const int*   tg = targets + (size_t)b * S;

  __shared__ float ls[64 * LSTR];         // 65 KB
  __shared__ int   tgs[S];

  for (int f = tid; f < 64 * 64; f += 512) {
    const int row = f >> 6, c4 = f & 63;
    int t = i0 + 1 + row; if (t > T - 1) t = T - 1;
    float4 v = ((const float4*)(lp + (size_t)t * V))[c4];
    *(float4*)&ls[row * LSTR + c4 * 4] = v;
  }
  for (int k = tid; k < S; k += 512) tgs[k] = tg[k];
  __syncthreads();

  const int w    = tid >> 6;
  const int lane = tid & 63;
  _Float16* gb = G + (size_t)b * NCTP * KP * 8;

  // 8 chunks x 8 j-values; lanes 0..50 write contiguous 816B runs
  for (int it = w; it < 64; it += 8) {
    const int cc = it >> 3;
    const int j  = it & 7;
    const int c  = tile * 8 + cc;
    if (c >= NCTP) continue;
    if (lane > 50) continue;
    const int k = 8 * lane + j;           // old row index 0..407
    const int e = (k < S) ? tgs[k] : 1;   // k>=400: blank/pad
    h8 hv;
    #pragma unroll
    for (int jj = 0; jj < 8; ++jj)
      hv[jj] = (_Float16)fexp2(ls[(cc * 8 + jj) * LSTR + e] * LOG2E);
    *(h8*)(gb + ((size_t)c * KP + j * 51 + lane) * 8) = hv;
  }
}

// ---------------- fwd/bwd meet-in-middle: ONE WAVE per (b,dir) --------------
// r14 post-mortem: the bottleneck was never prefetch distance -- it was the
// per-chunk CACHELINE footprint (9 loads x 64 lanes x 128B stride = 576
// lines/chunk, 16B used per 128B line; TCP outstanding-line tracker caps
// MLP so no software schedule can hide it).  With the permuted G layout the
// same 9 loads are lane-contiguous (~57 lines/chunk).  Simple 2-deep
// register ping-pong; lazy f16->f32 conversion keeps VGPR ~128.
// 16-state/lane band + per-lane exponent E validated r12-r14 (absmax=0).
__global__ __launch_bounds__(64)
void ctc_fb_kernel(const float* __restrict__ logp,
                   const int* __restrict__ targets,
                   const int* __restrict__ input_len,
                   const int* __restrict__ target_len,
                   const _Float16* __restrict__ G,
                   float* __restrict__ la,
                   float* __restrict__ lg)
{
  const int b    = blockIdx.x;
  const int dir  = blockIdx.y;
  const int lane = threadIdx.x & 63;
  const float* __restrict__ lp = logp + (size_t)b * T * V;
  const int il = input_len[b];
  const int tl = target_len[b];
  const int m  = il >> 1;
  const int* tg = targets + (size_t)b * S;

  const _Float16* Gb = G + (size_t)b * NCTP * KP * 8;
  // lane l consumes fragments p = j*51 + l (rows 8l..8l+7) + p=50 (blank).
  // Lanes >= 51 own only invalid states: clamp to l=50 (whose rows are the
  // blank pads 400..407 -- identical to the old krow clamp).
  const int lclamp = (lane < 50) ? lane : 50;

  float skF[8], skB[8];
  #pragma unroll
  for (int j = 0; j < 8; ++j) {
    const int k   = 8 * lane + j;
    const int kc  = k < S ? k : S - 1;
    const int km  = (k - 1) < 0 ? 0 : ((k - 1) < S ? (k - 1) : S - 1);
    skF[j] = (k > 0 && tg[kc] != tg[km]) ? 1.0f : 0.0f;
    const int k2  = k + 1;
    const int k2c = k2 < S ? k2 : S - 1;
    const int k2m = (k2 - 1) < S ? (k2 - 1) : S - 1;
    skB[j] = (tg[k2c] != tg[k2m]) ? 1.0f : 0.0f;
  }

  // ping-pong buffers: [0..7]=this lane's symbol rows, [8]=blank row
  h8 bufA[9], bufB[9];

  auto loadch = [&](h8 (&buf)[9], int c2) {
    if (c2 < 0) c2 = 0;
    if (c2 > NCTP - 1) c2 = NCTP - 1;
    const _Float16* src = Gb + (size_t)c2 * (KP * 8);
    #pragma unroll
    for (int j = 0; j < 8; ++j)
      buf[j] = *(const h8*)(src + (size_t)(j * 51 + lclamp) * 8);
    buf[8] = *(const h8*)(src + (size_t)50 * 8);   // blank (row 400)
  };

  if (dir == 0) {
    // ======================= FORWARD =======================
    float a[16];
    #pragma unroll
    for (int i = 0; i < 16; ++i) a[i] = 0.0f;
    int  E = 0;
    bool alive = (lane == 0);
    if (lane == 0) {
      a[0] = fexp2(lp[1] * LOG2E);          // t=0 blank
      a[1] = fexp2(lp[tg[0]] * LOG2E);      // t=0 first symbol
    }

    auto fwd_sub = [&](h8 (&buf)[9], const int c_) {
      h8 cur[9];
      #pragma unroll
      for (int r = 0; r < 9; ++r) cur[r] = buf[r];
      loadch(buf, c_ + 2);                  // refill this buffer (depth 2)

      const int E1 = wave_shr1_i(E);
      if (!alive) E = E1;
      int d = E1 - E; d = d > 126 ? 126 : (d < -126 ? -126 : d);
      const float f = ldexpf(1.0f, d);

      #pragma unroll
      for (int i = 0; i < 8; ++i) {
        const int t = 1 + c_ * CHK + i;
        if (t <= m) {                       // wave-uniform predicate
          const float pbi = (float)cur[8][i];
          const float h = wave_shr1(a[15]) * f;   // state 16l-1 (0 @ lane0)
          #pragma unroll
          for (int j = 7; j >= 0; --j) {    // descending: reads are pre-step
            const float psj = (float)cur[j][i];
            const float lo = j ? a[2 * j - 1] : h;
            a[2 * j + 1] = __builtin_fmaf(lo, skF[j],
                                          a[2 * j + 1] + a[2 * j]) * psj;
            a[2 * j]     = (a[2 * j] + lo) * pbi;
          }
        }
      }
      { // renorm
        float mx[8];
        #pragma unroll
        for (int q = 0; q < 8; ++q) mx[q] = fmaxf(a[2 * q], a[2 * q + 1]);
        #pragma unroll
        for (int q = 0; q < 4; ++q) mx[q] = fmaxf(mx[q], mx[q + 4]);
        const float m2 = fmaxf(fmaxf(mx[0], mx[1]), fmaxf(mx[2], mx[3]));
        int k = 0; (void)frexpf(m2, &k);
        #pragma unroll
        for (int i = 0; i < 16; ++i) a[i] = ldexpf(a[i], -k);
        E += k;
        alive = (m2 != 0.0f);
      }
    };

    loadch(bufA, 0); loadch(bufB, 1);
    const int NCH = (m + 7) >> 3;
    for (int c = 0; c < NCH; c += 2) {
      fwd_sub(bufA, c);
      fwd_sub(bufB, c + 1);
    }

    float* dst = la + (size_t)b * 1024 + 16 * lane;
    #pragma unroll
    for (int i = 0; i < 16; ++i) dst[i] = flog2(a[i]) + (float)E;
  } else {
    // ======================= BACKWARD =======================
    float g[16];
    const int s0 = 16 * lane;
    bool alive = false;
    #pragma unroll
    for (int i = 0; i < 16; ++i) {
      const int s = s0 + i;
      g[i] = (s == 2 * tl || s == 2 * tl - 1) ? 1.0f : 0.0f;
      alive = alive || (g[i] != 0.0f);
    }
    int E = 0;

    const int c_hi = (il - 2) >> 3;
    const int c_lo = m >> 3;

    auto bwd_sub = [&](h8 (&buf)[9], const int c_) {
      h8 cur[9];
      #pragma unroll
      for (int r = 0; r < 9; ++r) cur[r] = buf[r];
      loadch(buf, c_ - 2);                  // refill (descending, depth 2)

      const int E1 = wave_shl1_i(E);
      if (!alive) E = E1;
      int d = E1 - E; d = d > 126 ? 126 : (d < -126 ? -126 : d);
      const float f = ldexpf(1.0f, d);

      #pragma unroll
      for (int ii = 0; ii < 8; ++ii) {
        const int i = 7 - ii;
        const int row = 1 + c_ * CHK + i;   // emission row, processed hi->lo
        if (row > m && row < il) {          // wave-uniform predicate
          const float pbi = (float)cur[8][i];
          float pg[16];
          #pragma unroll
          for (int q = 0; q < 8; ++q) {
            pg[2 * q]     = g[2 * q]     * pbi;
            pg[2 * q + 1] = g[2 * q + 1] * (float)cur[q][i];
          }
          const float h0 = wave_shl1(pg[0]) * f;  // state 16(l+1)   (0 @ 63)
          const float h1 = wave_shl1(pg[1]) * f;  // state 16(l+1)+1 (0 @ 63)
          #pragma unroll
          for (int q = 0; q < 8; ++q) {
            const float u1 = (q < 7) ? pg[2 * q + 2] : h0;
            const float u2 = (q < 7) ? pg[2 * q + 3] : h1;
            g[2 * q + 1] = __builtin_fmaf(u2, skB[q], pg[2 * q + 1] + u1);
            g[2 * q]     = pg[2 * q] + pg[2 * q + 1];
          }
        }
      }
      {
        float mx[8];
        #pragma unroll
        for (int q = 0; q < 8; ++q) mx[q] = fmaxf(g[2 * q], g[2 * q + 1]);
        #pragma unroll
        for (int q = 0; q < 4; ++q) mx[q] = fmaxf(mx[q], mx[q + 4]);
        const float m2 = fmaxf(fmaxf(mx[0], mx[1]), fmaxf(mx[2], mx[3]));
        int k = 0; (void)frexpf(m2, &k);
        #pragma unroll
        for (int i = 0; i < 16; ++i) g[i] = ldexpf(g[i], -k);
        E += k;
        alive = (m2 != 0.0f);
      }
    };

    loadch(bufA, c_hi); loadch(bufB, c_hi - 1);
    for (int c = c_hi; c >= c_lo; c -= 2) {
      bwd_sub(bufA, c);
      bwd_sub(bufB, c - 1);
    }

    float* dst = lg + (size_t)b * 1024 + 16 * lane;
    #pragma unroll
    for (int i = 0; i < 16; ++i) dst[i] = flog2(g[i]) + (float)E;
  }
}

// ---------------- merge: loss_b = -ln sum_{s<Lb} 2^(la+lg), mean ------------
__global__ __launch_bounds__(64)
void ctc_merge_kernel(const float* __restrict__ la,
                      const float* __restrict__ lg,
                      const int* __restrict__ target_len,
                      float* __restrict__ out)
{
  const int b    = blockIdx.x;
  const int lane = threadIdx.x;
  const int tl = target_len[b];
  const int Lb = 2 * tl + 1;
  const float* A  = la + (size_t)b * 1024;
  const float* Gm = lg + (size_t)b * 1024;

  float vs[16];
  float vmax = -1e30f;
  #pragma unroll
  for (int r = 0; r < 16; ++r) {
    const int s = lane + 64 * r;
    float x = A[s] + Gm[s];
    x = (s < Lb) ? x : -1e30f;
    vs[r] = x;
    vmax = fmaxf(vmax, x);
  }
  #pragma unroll
  for (int o = 32; o > 0; o >>= 1) vmax = fmaxf(vmax, __shfl_xor(vmax, o, 64));
  float sum = 0.0f;
  #pragma unroll
  for (int r = 0; r < 16; ++r) sum += fexp2(vs[r] - vmax);
  #pragma unroll
  for (int o = 32; o > 0; o >>= 1) sum += __shfl_xor(sum, o, 64);
  if (lane == 0) {
    const float ll = (vmax + flog2(sum)) * LN2;
    float loss = -ll;
    if (!(loss < 1e29f)) loss = 0.0f;
    atomicAdd(out, loss / ((float)tl * (float)B));
  }
}

// ---------------- fallback: round-6 kernel (validated), if ws too small -----
__global__ __launch_bounds__(NW7 * 64)
void ctc_alpha7_kernel(const float* __restrict__ logp,
                       const int* __restrict__ targets,
                       const int* __restrict__ input_len,
                       const int* __restrict__ target_len,
                       float* __restrict__ out)
{
  const int b    = blockIdx.x;
  const int tid  = threadIdx.x;
  const int w    = tid >> 6;
  const int lane = tid & 63;
  const bool lane0 = (lane == 0);
  const float* __restrict__ lp = logp + (size_t)b * T * V;
  const int il = input_len[b];
  const int tl = target_len[b];
  const int Lb = 2 * tl + 1;

  __shared__ float bnd[NW7 - 1][NCT7 * BST7];
  __shared__ int   cnt[NW7 - 1];
  __shared__ float pblk[T];
  __shared__ float afin[NW7 * 64 * 2];

  if (tid < NW7 - 1) cnt[tid] = 0;

  const int* tg = targets + (size_t)b * S;
  const int k1 = (tid < S) ? tid : (S - 1);
  const int e1 = tg[k1];
  const float sk1 = (k1 == 0 || e1 != tg[k1 - 1]) ? 1.0f : 0.0f;

  for (int i = tid; i < T; i += NW7 * 64) {
    int t = (i + 1 < T) ? (i + 1) : (T - 1);
    pblk[i] = fexp2(lp[(size_t)t * V + 1] * LOG2E);
  }
  __syncthreads();

  const bool active = (w * 128) < Lb;
  if (active) {
    float a0 = 0.0f, a1 = 0.0f;
    int   E  = 0;
    if (tid == 0) { a0 = fexp2(lp[1] * LOG2E); a1 = fexp2(lp[e1] * LOG2E); }

    float tokL[CHK];
    #pragma unroll
    for (int i = 0; i < CHK; ++i) tokL[i] = lp[(size_t)(1 + i) * V + e1];

    const int NCH = (il - 1 + CHK - 1) / CHK;
    for (int c = 0; c < NCH; ++c) {
      const int t0 = 1 + c * CHK;
      float tokP[CHK];
      #pragma unroll
      for (int i = 0; i < CHK; ++i) tokP[i] = fexp2(tokL[i] * LOG2E);
      float nl[CHK];
      if (c + 1 < NCT7) {
        #pragma unroll
        for (int i = 0; i < CHK; ++i) {
          int tt = t0 + CHK + i; if (tt > T - 1) tt = T - 1;
          nl[i] = lp[(size_t)tt * V + e1];
        }
      }
      float pbk[CHK];
      {
        float4 q0 = *(const float4*)&pblk[c * CHK];
        float4 q1 = *(const float4*)&pblk[c * CHK + 4];
        pbk[0]=q0.x; pbk[1]=q0.y; pbk[2]=q0.z; pbk[3]=q0.w;
        pbk[4]=q1.x; pbk[5]=q1.y; pbk[6]=q1.z; pbk[7]=q1.w;
      }
      float bq[CHK];
      int Ep = 0;
      if (w > 0) {
        while (__hip_atomic_load(&cnt[w - 1], __ATOMIC_ACQUIRE,
                                 __HIP_MEMORY_SCOPE_WORKGROUP) < c + 1)
          __builtin_amdgcn_s_sleep(1);
        const float* src = &bnd[w - 1][c * BST7];
        float4 q0 = *(const float4*)(src);
        float4 q1 = *(const float4*)(src + 4);
        bq[0]=q0.x; bq[1]=q0.y; bq[2]=q0.z; bq[3]=q0.w;
        bq[4]=q1.x; bq[5]=q1.y; bq[6]=q1.z; bq[7]=q1.w;
        Ep = __float_as_int(src[8]);
      } else {
        #pragma unroll
        for (int i = 0; i < CHK; ++i) bq[i] = 0.0f;
      }
      const float mz  = fmaxf(a0, a1);
      const int   E1o = __shfl_up(E, 1);
      const int   E8  = __shfl_up(E, 8);
      const int   E9  = __shfl_up(E, 9);
      const float mz1 = __shfl_up(mz, 1);
      if (mz == 0.0f) E = (lane < 8) ? Ep : E8;
      int E1 = (mz1 == 0.0f) ? ((lane <= 8) ? Ep : E9) : E1o;
      if (lane0) E1 = (w == 0) ? E : Ep;
      int d = E1 - E; d = d > 126 ? 126 : (d < -126 ? -126 : d);
      const float f = ldexpf(1.0f, d);
      const float a1s = a1;
      float pub[CHK];
      #pragma unroll
      for (int i = 0; i < CHK; ++i) {
        const int t = t0 + i;
        if (t < il) {
          float hl = wave_shr1(a1);
          hl = lane0 ? bq[i] : hl;
          hl *= f;
          float s01 = a1 + a0;
          a1 = __builtin_fmaf(hl, sk1, s01) * tokP[i];
          a0 = (a0 + hl) * pbk[i];
        }
        pub[i] = a1;
      }
      if (w < NW7 - 1 && lane == 63) {
        float* dst = &bnd[w][c * BST7];
        dst[0] = a1s;
        #pragma unroll
        for (int i = 0; i < CHK - 1; ++i) dst[1 + i] = pub[i];
        dst[8] = __int_as_float(E);
        __hip_atomic_store(&cnt[w], c + 1, __ATOMIC_RELEASE,
                           __HIP_MEMORY_SCOPE_WORKGROUP);
      }
      {
        float m2 = fmaxf(a0, a1);
        int k = 0;
        (void)frexpf(m2, &k);
        a0 = ldexpf(a0, -k);
        a1 = ldexpf(a1, -k);
        E += k;
      }
      #pragma unroll
      for (int i = 0; i < CHK; ++i) tokL[i] = nl[i];
    }
    afin[2 * tid]     = flog2(a0) + (float)E;
    afin[2 * tid + 1] = flog2(a1) + (float)E;
  }
  __syncthreads();

  if (tid == 0) {
    const float x = afin[2 * tl];
    const float y = afin[2 * tl - 1];
    const float mm = fmaxf(x, y);
    const float ll = (mm + flog2(fexp2(x - mm) + fexp2(y - mm))) * LN2;
    float loss = -ll;
    if (!(loss < 1e29f)) loss = 0.0f;
    atomicAdd(out, loss / ((float)tl * (float)B));
  }
}

__global__ void ctc_zero_kernel(float* __restrict__ out) { out[0] = 0.0f; }

extern "C" void kernel_launch(void* const* d_in, const int* in_sizes, int n_in,
                              void* d_out, int out_size, void* d_ws, size_t ws_size,
                              hipStream_t stream) {
  const float* logp    = (const float*)d_in[0];
  const int*   targets = (const int*)d_in[1];
  const int*   il      = (const int*)d_in[2];
  const int*   tl      = (const int*)d_in[3];
  float* out = (float*)d_out;

  ctc_zero_kernel<<<1, 1, 0, stream>>>(out);
  if (ws_size >= REQBYTES) {
    _Float16* G  = (_Float16*)d_ws;
    float*    la = (float*)d_ws + LAOFF;
    float*    lg = (float*)d_ws + LGOFF;
    ctc_gather_kernel<<<dim3(32, B), 512, 0, stream>>>(logp, targets, G);
    ctc_fb_kernel<<<dim3(B, 2), 64, 0, stream>>>(logp, targets, il, tl, G, la, lg);
    ctc_merge_kernel<<<B, 64, 0, stream>>>(la, lg, tl, out);
  } else {
    ctc_alpha7_kernel<<<B, NW7 * 64, 0, stream>>>(logp, targets, il, tl, out);
  }
}